// Round 1
// baseline (7810.529 us; speedup 1.0000x reference)
//
#include <hip/hip_runtime.h>
#include <stdint.h>

#define BATCH   4096
#define KDIM    4096      // 2*2048 encode contraction
#define FDIM    16384
#define DDIM    4096      // 2*2048 decode output per row
#define TOPK    64

// ---------------------------------------------------------------------------
// Encode: C = relu(A @ B + bias), A=(BATCH,KDIM) rm, B=(KDIM,FDIM) rm, f32.
// 128x128x16 tile, 256 threads, 8x8 microtile.
// ---------------------------------------------------------------------------
#define BM 128
#define BN 128
#define BK 16

__global__ __launch_bounds__(256) void encode_gemm(
    const float* __restrict__ A,
    const float* __restrict__ B,
    const float* __restrict__ bias,
    float* __restrict__ C)
{
    __shared__ float As[BK][BM];   // transposed A tile
    __shared__ float Bs[BK][BN];

    // XCD-aware swizzle (grid = 4096, divisible by 8)
    int nwg = gridDim.x;
    int cpx = nwg >> 3;
    int bid = blockIdx.x;
    int wg  = (bid & 7) * cpx + (bid >> 3);

    const int nbn = FDIM / BN;            // 128
    int bm = (wg / nbn) * BM;
    int bn = (wg % nbn) * BN;

    int tid = threadIdx.x;
    int tn  = tid & 15;    // N fastest -> coalesced C stores
    int tm  = tid >> 4;

    float acc[8][8];
    #pragma unroll
    for (int i = 0; i < 8; ++i)
        #pragma unroll
        for (int j = 0; j < 8; ++j) acc[i][j] = 0.0f;

    for (int kt = 0; kt < KDIM; kt += BK) {
        // A tile: 128 rows x 16 k = 512 float4
        #pragma unroll
        for (int t = 0; t < 2; ++t) {
            int s   = tid + t * 256;
            int row = s >> 2;
            int c4  = (s & 3) << 2;
            const float4 a = *(const float4*)(A + (size_t)(bm + row) * KDIM + kt + c4);
            As[c4 + 0][row] = a.x;
            As[c4 + 1][row] = a.y;
            As[c4 + 2][row] = a.z;
            As[c4 + 3][row] = a.w;
        }
        // B tile: 16 rows x 128 n = 512 float4
        #pragma unroll
        for (int t = 0; t < 2; ++t) {
            int s   = tid + t * 256;
            int row = s >> 5;
            int c4  = (s & 31) << 2;
            *(float4*)&Bs[row][c4] =
                *(const float4*)(B + (size_t)(kt + row) * FDIM + bn + c4);
        }
        __syncthreads();

        #pragma unroll
        for (int k = 0; k < BK; ++k) {
            float av[8], bv[8];
            *(float4*)&av[0] = *(const float4*)&As[k][tm * 8];
            *(float4*)&av[4] = *(const float4*)&As[k][tm * 8 + 4];
            *(float4*)&bv[0] = *(const float4*)&Bs[k][tn * 8];
            *(float4*)&bv[4] = *(const float4*)&Bs[k][tn * 8 + 4];
            #pragma unroll
            for (int i = 0; i < 8; ++i)
                #pragma unroll
                for (int j = 0; j < 8; ++j)
                    acc[i][j] = fmaf(av[i], bv[j], acc[i][j]);
        }
        __syncthreads();
    }

    float bb[8];
    *(float4*)&bb[0] = *(const float4*)(bias + bn + tn * 8);
    *(float4*)&bb[4] = *(const float4*)(bias + bn + tn * 8 + 4);

    #pragma unroll
    for (int i = 0; i < 8; ++i) {
        int row = bm + tm * 8 + i;
        float* crow = C + (size_t)row * FDIM + bn + tn * 8;
        float r[8];
        #pragma unroll
        for (int j = 0; j < 8; ++j) {
            float v = acc[i][j] + bb[j];
            r[j] = (v > 0.0f) ? v : 0.0f;   // guaranteed +0.0 (bit pattern 0)
        }
        *(float4*)(crow)     = *(float4*)&r[0];
        *(float4*)(crow + 4) = *(float4*)&r[4];
    }
}

// ---------------------------------------------------------------------------
// Top-k: exact radix select of 64th-largest per row (values are relu'd >= 0,
// so float bits order as uint32). Ties kept by lowest index (matches
// jax.lax.top_k + scatter). Rewrites the row in place: non-selected -> 0.
// ---------------------------------------------------------------------------
__global__ __launch_bounds__(256) void topk_kernel(float* __restrict__ feat)
{
    int b   = blockIdx.x;
    int tid = threadIdx.x;
    uint32_t* urow = (uint32_t*)(feat + (size_t)b * FDIM);

    __shared__ uint32_t hist[256];
    __shared__ uint32_t scan[256];
    __shared__ uint32_t sh_prefix, sh_rem;

    uint32_t prefix = 0;
    uint32_t rem    = TOPK;

    for (int byt = 3; byt >= 0; --byt) {
        hist[tid] = 0;
        __syncthreads();
        int shift_hi = (byt + 1) * 8;
        for (int i = tid; i < FDIM; i += 256) {
            uint32_t u = urow[i];
            bool match = (byt == 3) || ((u >> shift_hi) == prefix);
            if (match) atomicAdd(&hist[(u >> (byt * 8)) & 255u], 1u);
        }
        __syncthreads();
        // descending-digit inclusive scan: scan[t] = count(digit >= 255-t)
        scan[tid] = hist[255 - tid];
        __syncthreads();
        #pragma unroll
        for (int ofs = 1; ofs < 256; ofs <<= 1) {
            uint32_t tv = (tid >= ofs) ? scan[tid - ofs] : 0u;
            __syncthreads();
            scan[tid] += tv;
            __syncthreads();
        }
        uint32_t cum  = scan[tid];
        uint32_t prev = (tid == 0) ? 0u : scan[tid - 1];
        if (cum >= rem && prev < rem) {
            sh_prefix = (prefix << 8) | (uint32_t)(255 - tid);
            sh_rem    = rem - prev;
        }
        __syncthreads();
        prefix = sh_prefix;
        rem    = sh_rem;
        __syncthreads();
    }

    uint32_t T       = prefix;  // bit pattern of the 64th-largest value
    uint32_t need_eq = rem;     // how many values == T to keep (lowest index)

    // phase 2: per-thread contiguous chunk, stable equal-rank via block scan
    const int CHUNK = FDIM / 256;   // 64
    int base = tid * CHUNK;

    uint32_t myeq = 0;
    for (int i = 0; i < CHUNK; i += 4) {
        uint4 u = *(const uint4*)(urow + base + i);
        myeq += (u.x == T) + (u.y == T) + (u.z == T) + (u.w == T);
    }
    scan[tid] = myeq;
    __syncthreads();
    #pragma unroll
    for (int ofs = 1; ofs < 256; ofs <<= 1) {
        uint32_t tv = (tid >= ofs) ? scan[tid - ofs] : 0u;
        __syncthreads();
        scan[tid] += tv;
        __syncthreads();
    }
    uint32_t eqrank = scan[tid] - myeq;   // exclusive prefix (index-ordered)

    for (int i = 0; i < CHUNK; i += 4) {
        uint4 u = *(const uint4*)(urow + base + i);
        uint32_t o[4] = {u.x, u.y, u.z, u.w};
        #pragma unroll
        for (int j = 0; j < 4; ++j) {
            bool keep;
            if (o[j] > T)       keep = true;
            else if (o[j] == T) { keep = (eqrank < need_eq); eqrank++; }
            else                keep = false;
            if (!keep) o[j] = 0u;
        }
        uint4 w; w.x = o[0]; w.y = o[1]; w.z = o[2]; w.w = o[3];
        *(uint4*)(urow + base + i) = w;
    }
}

// ---------------------------------------------------------------------------
// Decode: one block per row. Compact the <=64 nonzeros from the features row,
// then recon[b] = sum_f val_f * (W_dec[f] * dec_mask[f]) + b_dec.
// ---------------------------------------------------------------------------
__global__ __launch_bounds__(256) void decode_kernel(
    const float* __restrict__ feat,
    const float* __restrict__ Wdec,    // (FDIM, 4096)
    const float* __restrict__ bdec,    // (4096)
    const float* __restrict__ dmask,   // (FDIM, 2)
    float* __restrict__ recon)         // (BATCH, 4096)
{
    int b   = blockIdx.x;
    int tid = threadIdx.x;

    __shared__ int   sidx[TOPK];
    __shared__ float sv0[TOPK], sv1[TOPK];
    __shared__ int   cnt;
    if (tid == 0) cnt = 0;
    __syncthreads();

    const float* row = feat + (size_t)b * FDIM;
    const int CHUNK = FDIM / 256;
    int base = tid * CHUNK;
    for (int i = 0; i < CHUNK; i += 4) {
        float4 v = *(const float4*)(row + base + i);
        float vv[4] = {v.x, v.y, v.z, v.w};
        #pragma unroll
        for (int j = 0; j < 4; ++j) {
            if (vv[j] != 0.0f) {
                int s = atomicAdd(&cnt, 1);
                int f = base + i + j;
                sidx[s] = f;
                sv0[s]  = vv[j] * dmask[f * 2 + 0];
                sv1[s]  = vv[j] * dmask[f * 2 + 1];
            }
        }
    }
    __syncthreads();
    int n = cnt;

    float4 acc[4];
    const float4* b4 = (const float4*)bdec;
    #pragma unroll
    for (int j = 0; j < 4; ++j) acc[j] = b4[tid + j * 256];

    for (int t = 0; t < n; ++t) {
        int f = sidx[t];
        const float4* w = (const float4*)(Wdec + (size_t)f * DDIM);
        float s0 = sv0[t], s1 = sv1[t];
        #pragma unroll
        for (int j = 0; j < 4; ++j) {
            float s = (j < 2) ? s0 : s1;   // elems <2048 -> model 0
            float4 wv = w[tid + j * 256];
            acc[j].x = fmaf(s, wv.x, acc[j].x);
            acc[j].y = fmaf(s, wv.y, acc[j].y);
            acc[j].z = fmaf(s, wv.z, acc[j].z);
            acc[j].w = fmaf(s, wv.w, acc[j].w);
        }
    }

    float4* out = (float4*)(recon + (size_t)b * DDIM);
    #pragma unroll
    for (int j = 0; j < 4; ++j) out[tid + j * 256] = acc[j];
}

// ---------------------------------------------------------------------------
extern "C" void kernel_launch(void* const* d_in, const int* in_sizes, int n_in,
                              void* d_out, int out_size, void* d_ws, size_t ws_size,
                              hipStream_t stream)
{
    const float* x     = (const float*)d_in[0];
    const float* Wenc  = (const float*)d_in[1];
    const float* benc  = (const float*)d_in[2];
    const float* Wdec  = (const float*)d_in[3];
    const float* bdec  = (const float*)d_in[4];
    const float* dmask = (const float*)d_in[5];

    float* recon = (float*)d_out;
    float* feat  = recon + (size_t)BATCH * DDIM;   // pre/features staged in d_out

    encode_gemm<<<dim3((BATCH / BM) * (FDIM / BN)), 256, 0, stream>>>(x, Wenc, benc, feat);
    topk_kernel<<<dim3(BATCH), 256, 0, stream>>>(feat);
    decode_kernel<<<dim3(BATCH), 256, 0, stream>>>(feat, Wdec, bdec, dmask, recon);
}

// Round 4
// 3870.982 us; speedup vs baseline: 2.0177x; 2.0177x over previous
//
#include <hip/hip_runtime.h>
#include <stdint.h>

#define BATCH   4096
#define KDIM    4096      // 2*2048 encode contraction
#define FDIM    16384
#define DDIM    4096
#define TOPK    64

typedef _Float16 half4v __attribute__((ext_vector_type(4)));
typedef _Float16 half8v __attribute__((ext_vector_type(8)));
typedef float    f32x4  __attribute__((ext_vector_type(4)));

// ---------------------------------------------------------------------------
// Encode: C = relu(A @ B + bias) via f16x2 split MFMA (3 products: hh, hl, lh).
// Validated in round 3 (recon passed => GEMM correct to ~1e-5).
// ---------------------------------------------------------------------------
__global__ __launch_bounds__(256) void encode_mfma(
    const float* __restrict__ A,
    const float* __restrict__ B,
    const float* __restrict__ bias,
    float* __restrict__ C)
{
    __shared__ _Float16 Ah[128 * 32];   // [m][k], chunk-swizzled rows of 64B
    __shared__ _Float16 Al[128 * 32];
    __shared__ _Float16 Bh[128 * 32];   // 8 subtiles [16col][32k], swizzled
    __shared__ _Float16 Bl[128 * 32];

    int nwg = gridDim.x;
    int cpx = nwg >> 3;
    int bid = blockIdx.x;
    int wg  = (bid & 7) * cpx + (bid >> 3);

    int bm = (wg >> 7) << 7;
    int bn = (wg & 127) << 7;

    int tid  = threadIdx.x;
    int wave = tid >> 6, lane = tid & 63;
    int wr = wave >> 1, wc = wave & 1;          // 2x2 waves of 64x64
    int lrow = lane & 15, lgrp = lane >> 4;

    int colw = tid & 127;     // B staging: column within tile
    int kh   = tid >> 7;      // k-half
    int nbw  = colw >> 4;
    int colb = colw & 15;

    const float* Arow = A + (size_t)bm * KDIM;

    float4 areg[4];
    float  breg[16];
    #pragma unroll
    for (int i = 0; i < 4; ++i) {
        int idx = tid + i * 256;
        areg[i] = *(const float4*)(Arow + (size_t)(idx >> 3) * KDIM + ((idx & 7) << 2));
    }
    #pragma unroll
    for (int kk = 0; kk < 16; ++kk)
        breg[kk] = B[(size_t)(kh * 16 + kk) * FDIM + bn + colw];

    f32x4 zero = {0.0f, 0.0f, 0.0f, 0.0f};
    f32x4 acc[4][4];
    #pragma unroll
    for (int mf = 0; mf < 4; ++mf)
        #pragma unroll
        for (int nf = 0; nf < 4; ++nf) acc[mf][nf] = zero;

    for (int kt = 0; kt < KDIM; kt += 32) {
        __syncthreads();

        #pragma unroll
        for (int i = 0; i < 4; ++i) {
            int idx = tid + i * 256;
            int m   = idx >> 3;
            int g   = (idx & 7) >> 1;
            int hf  = (idx & 1) << 2;
            int off = m * 32 + ((g ^ ((m >> 1) & 3)) << 3) + hf;
            float v[4] = {areg[i].x, areg[i].y, areg[i].z, areg[i].w};
            half4v h1, h2;
            #pragma unroll
            for (int j = 0; j < 4; ++j) {
                _Float16 h = (_Float16)v[j];
                h1[j] = h;
                h2[j] = (_Float16)(v[j] - (float)h);
            }
            *(half4v*)&Ah[off] = h1;
            *(half4v*)&Al[off] = h2;
        }
        {
            half8v g0h, g0l, g1h, g1l;
            #pragma unroll
            for (int kk = 0; kk < 8; ++kk) {
                _Float16 h = (_Float16)breg[kk];
                g0h[kk] = h;
                g0l[kk] = (_Float16)(breg[kk] - (float)h);
                _Float16 h2 = (_Float16)breg[8 + kk];
                g1h[kk] = h2;
                g1l[kk] = (_Float16)(breg[8 + kk] - (float)h2);
            }
            int g0 = kh * 2, g1 = kh * 2 + 1;
            int off0 = nbw * 512 + ((colb * 4 + (g0 ^ ((colb >> 1) & 3))) << 3);
            int off1 = nbw * 512 + ((colb * 4 + (g1 ^ ((colb >> 1) & 3))) << 3);
            *(half8v*)&Bh[off0] = g0h;
            *(half8v*)&Bl[off0] = g0l;
            *(half8v*)&Bh[off1] = g1h;
            *(half8v*)&Bl[off1] = g1l;
        }
        __syncthreads();

        if (kt + 32 < KDIM) {
            #pragma unroll
            for (int i = 0; i < 4; ++i) {
                int idx = tid + i * 256;
                areg[i] = *(const float4*)(Arow + (size_t)(idx >> 3) * KDIM + kt + 32 + ((idx & 7) << 2));
            }
            #pragma unroll
            for (int kk = 0; kk < 16; ++kk)
                breg[kk] = B[(size_t)(kt + 32 + kh * 16 + kk) * FDIM + bn + colw];
        }

        half8v ahf[4], alf[4], bhf[4], blf[4];
        #pragma unroll
        for (int mf = 0; mf < 4; ++mf) {
            int m   = wr * 64 + mf * 16 + lrow;
            int off = m * 32 + ((lgrp ^ ((m >> 1) & 3)) << 3);
            ahf[mf] = *(half8v*)&Ah[off];
            alf[mf] = *(half8v*)&Al[off];
        }
        #pragma unroll
        for (int nf = 0; nf < 4; ++nf) {
            int nb  = wc * 4 + nf;
            int off = nb * 512 + ((lrow * 4 + (lgrp ^ ((lrow >> 1) & 3))) << 3);
            bhf[nf] = *(half8v*)&Bh[off];
            blf[nf] = *(half8v*)&Bl[off];
        }

        #pragma unroll
        for (int mf = 0; mf < 4; ++mf)
            #pragma unroll
            for (int nf = 0; nf < 4; ++nf) {
                acc[mf][nf] = __builtin_amdgcn_mfma_f32_16x16x32_f16(ahf[mf], bhf[nf], acc[mf][nf], 0, 0, 0);
                acc[mf][nf] = __builtin_amdgcn_mfma_f32_16x16x32_f16(ahf[mf], blf[nf], acc[mf][nf], 0, 0, 0);
                acc[mf][nf] = __builtin_amdgcn_mfma_f32_16x16x32_f16(alf[mf], bhf[nf], acc[mf][nf], 0, 0, 0);
            }
    }

    #pragma unroll
    for (int nf = 0; nf < 4; ++nf) {
        int col = bn + wc * 64 + nf * 16 + lrow;
        float bb = bias[col];
        #pragma unroll
        for (int mf = 0; mf < 4; ++mf) {
            int row0 = bm + wr * 64 + mf * 16 + lgrp * 4;
            #pragma unroll
            for (int r = 0; r < 4; ++r) {
                float v = acc[mf][nf][r] + bb;
                C[(size_t)(row0 + r) * FDIM + col] = (v > 0.0f) ? v : 0.0f;
            }
        }
    }
}

// ---------------------------------------------------------------------------
// Top-k with band + f64 refinement.
// Radix-select T_fast (64th largest). Values > T+eps: definitely kept.
// Values < T-eps: zeroed. In-band: recompute exact f64 dot, select the
// needed (64 - D) by (exact desc, index asc) — matches lax.top_k tie-break.
// eps = 2e-3 is >> fast-path max error (~3e-5) and << typical gaps (7e-3).
// ---------------------------------------------------------------------------
#define EPS_BAND 2e-3f
#define MAXCAND  32

__global__ __launch_bounds__(256) void topk_refine(
    float* __restrict__ feat,
    const float* __restrict__ x,      // (BATCH, KDIM)
    const float* __restrict__ Wenc,   // (KDIM, FDIM)
    const float* __restrict__ benc)   // (FDIM)
{
    int b   = blockIdx.x;
    int tid = threadIdx.x;
    float*    frow = feat + (size_t)b * FDIM;
    uint32_t* urow = (uint32_t*)frow;

    __shared__ uint32_t hist[256];
    __shared__ uint32_t scan[256];
    __shared__ uint32_t sh_prefix, sh_rem;

    // ---- phase 1: radix select bits of the 64th-largest value ----
    uint32_t prefix = 0;
    uint32_t rem    = TOPK;
    for (int byt = 3; byt >= 0; --byt) {
        hist[tid] = 0;
        __syncthreads();
        int shift_hi = (byt + 1) * 8;
        for (int i = tid; i < FDIM; i += 256) {
            uint32_t u = urow[i];
            bool match = (byt == 3) || ((u >> shift_hi) == prefix);
            if (match) atomicAdd(&hist[(u >> (byt * 8)) & 255u], 1u);
        }
        __syncthreads();
        scan[tid] = hist[255 - tid];
        __syncthreads();
        #pragma unroll
        for (int ofs = 1; ofs < 256; ofs <<= 1) {
            uint32_t tv = (tid >= ofs) ? scan[tid - ofs] : 0u;
            __syncthreads();
            scan[tid] += tv;
            __syncthreads();
        }
        uint32_t cum  = scan[tid];
        uint32_t prev = (tid == 0) ? 0u : scan[tid - 1];
        if (cum >= rem && prev < rem) {
            sh_prefix = (prefix << 8) | (uint32_t)(255 - tid);
            sh_rem    = rem - prev;
        }
        __syncthreads();
        prefix = sh_prefix;
        rem    = sh_rem;
        __syncthreads();
    }

    float T  = __uint_as_float(prefix);
    float hi = T + EPS_BAND;
    float lo = T - EPS_BAND;

    // ---- phase 2: band classify ----
    __shared__ int   s_ncand, s_ndef;
    __shared__ int   s_cidx[MAXCAND];
    __shared__ float s_cval[MAXCAND];
    __shared__ int   s_sel[MAXCAND];
    if (tid == 0) { s_ncand = 0; s_ndef = 0; }
    __syncthreads();

    int base  = tid * 64;
    int mydef = 0;
    for (int i = 0; i < 64; i += 4) {
        float4 v = *(float4*)(frow + base + i);
        float vv[4] = {v.x, v.y, v.z, v.w};
        #pragma unroll
        for (int j = 0; j < 4; ++j) {
            float val = vv[j];
            if (val > hi) {
                ++mydef;                      // definitely top-64, keep
            } else if (val >= lo) {
                int s = atomicAdd(&s_ncand, 1);
                if (s < MAXCAND) { s_cidx[s] = base + i + j; s_cval[s] = val; }
                vv[j] = 0.0f;                 // zero now, maybe restore later
            } else {
                vv[j] = 0.0f;                 // definitely out
            }
        }
        float4 w; w.x = vv[0]; w.y = vv[1]; w.z = vv[2]; w.w = vv[3];
        *(float4*)(frow + base + i) = w;
    }
    atomicAdd(&s_ndef, mydef);
    __syncthreads();

    int A    = (s_ncand < MAXCAND) ? s_ncand : MAXCAND;
    int need = TOPK - s_ndef;                 // >= 1, <= A (by margin argument)

    // ---- phase 3: f64 refinement when the band has more members than slots ----
    __shared__ double red[256];
    __shared__ double s_exact[MAXCAND];
    if (A > need) {
        const float* xr = x + (size_t)b * KDIM;
        for (int c = 0; c < A; ++c) {
            int f = s_cidx[c];
            double s = 0.0;
            #pragma unroll
            for (int i = 0; i < 16; ++i) {
                int k = tid + i * 256;
                s += (double)xr[k] * (double)Wenc[(size_t)k * FDIM + f];
            }
            red[tid] = s;
            __syncthreads();
            for (int ofs = 128; ofs > 0; ofs >>= 1) {
                if (tid < ofs) red[tid] += red[tid + ofs];
                __syncthreads();
            }
            if (tid == 0) s_exact[c] = red[0] + (double)benc[f];
            __syncthreads();
        }
        if (tid == 0) {
            for (int c = 0; c < A; ++c) s_sel[c] = 0;
            for (int r = 0; r < need; ++r) {
                int best = -1;
                for (int c = 0; c < A; ++c) {
                    if (s_sel[c]) continue;
                    if (best < 0 || s_exact[c] > s_exact[best] ||
                        (s_exact[c] == s_exact[best] && s_cidx[c] < s_cidx[best]))
                        best = c;
                }
                if (best >= 0) s_sel[best] = 1;
            }
        }
    } else {
        if (tid == 0)
            for (int c = 0; c < A; ++c) s_sel[c] = 1;   // forced: restore all
    }
    __syncthreads();

    // ---- phase 4: restore selected in-band features ----
    if (tid < A && s_sel[tid]) frow[s_cidx[tid]] = s_cval[tid];
}

// ---------------------------------------------------------------------------
// Decode: one block per row; compact <=64 nonzeros; accumulate masked W_dec.
// ---------------------------------------------------------------------------
__global__ __launch_bounds__(256) void decode_kernel(
    const float* __restrict__ feat,
    const float* __restrict__ Wdec,
    const float* __restrict__ bdec,
    const float* __restrict__ dmask,
    float* __restrict__ recon)
{
    int b   = blockIdx.x;
    int tid = threadIdx.x;

    __shared__ int   sidx[TOPK];
    __shared__ float sv0[TOPK], sv1[TOPK];
    __shared__ int   cnt;
    if (tid == 0) cnt = 0;
    __syncthreads();

    const float* row = feat + (size_t)b * FDIM;
    const int CHUNK = FDIM / 256;
    int base = tid * CHUNK;
    for (int i = 0; i < CHUNK; i += 4) {
        float4 v = *(const float4*)(row + base + i);
        float vv[4] = {v.x, v.y, v.z, v.w};
        #pragma unroll
        for (int j = 0; j < 4; ++j) {
            if (vv[j] != 0.0f) {
                int s = atomicAdd(&cnt, 1);
                int f = base + i + j;
                sidx[s] = f;
                sv0[s]  = vv[j] * dmask[f * 2 + 0];
                sv1[s]  = vv[j] * dmask[f * 2 + 1];
            }
        }
    }
    __syncthreads();
    int n = cnt;

    float4 acc[4];
    const float4* b4 = (const float4*)bdec;
    #pragma unroll
    for (int j = 0; j < 4; ++j) acc[j] = b4[tid + j * 256];

    for (int t = 0; t < n; ++t) {
        int f = sidx[t];
        const float4* w = (const float4*)(Wdec + (size_t)f * DDIM);
        float s0 = sv0[t], s1 = sv1[t];
        #pragma unroll
        for (int j = 0; j < 4; ++j) {
            float s = (j < 2) ? s0 : s1;
            float4 wv = w[tid + j * 256];
            acc[j].x = fmaf(s, wv.x, acc[j].x);
            acc[j].y = fmaf(s, wv.y, acc[j].y);
            acc[j].z = fmaf(s, wv.z, acc[j].z);
            acc[j].w = fmaf(s, wv.w, acc[j].w);
        }
    }

    float4* out = (float4*)(recon + (size_t)b * DDIM);
    #pragma unroll
    for (int j = 0; j < 4; ++j) out[tid + j * 256] = acc[j];
}

// ---------------------------------------------------------------------------
extern "C" void kernel_launch(void* const* d_in, const int* in_sizes, int n_in,
                              void* d_out, int out_size, void* d_ws, size_t ws_size,
                              hipStream_t stream)
{
    const float* x     = (const float*)d_in[0];
    const float* Wenc  = (const float*)d_in[1];
    const float* benc  = (const float*)d_in[2];
    const float* Wdec  = (const float*)d_in[3];
    const float* bdec  = (const float*)d_in[4];
    const float* dmask = (const float*)d_in[5];

    float* recon = (float*)d_out;
    float* feat  = recon + (size_t)BATCH * DDIM;

    encode_mfma<<<dim3((BATCH / 128) * (FDIM / 128)), 256, 0, stream>>>(x, Wenc, benc, feat);
    topk_refine<<<dim3(BATCH), 256, 0, stream>>>(feat, x, Wenc, benc);
    decode_kernel<<<dim3(BATCH), 256, 0, stream>>>(feat, Wdec, bdec, dmask, recon);
}

// Round 7
// 3366.607 us; speedup vs baseline: 2.3200x; 1.1498x over previous
//
#include <hip/hip_runtime.h>
#include <stdint.h>

#define BATCH   4096
#define KDIM    4096      // 2*2048 encode contraction
#define FDIM    16384
#define DDIM    4096
#define TOPK    64

typedef _Float16 half4v __attribute__((ext_vector_type(4)));
typedef _Float16 half8v __attribute__((ext_vector_type(8)));
typedef float    f32x4  __attribute__((ext_vector_type(4)));

// ---------------------------------------------------------------------------
// Encode: C = relu(A @ B + bias) via f16x2 split MFMA (3 products: hh, hl, lh).
// Round-4 validated body. ONLY change: bn-MAJOR block order — with the XCD
// swizzle each XCD owns a disjoint 1/8 slice of B's columns, so B is fetched
// from HBM exactly once device-wide and A (64MB) stays L3-resident.
// ---------------------------------------------------------------------------
__global__ __launch_bounds__(256) void encode_mfma(
    const float* __restrict__ A,
    const float* __restrict__ B,
    const float* __restrict__ bias,
    float* __restrict__ C)
{
    __shared__ _Float16 Ah[128 * 32];   // [m][k], chunk-swizzled rows of 64B
    __shared__ _Float16 Al[128 * 32];
    __shared__ _Float16 Bh[128 * 32];   // 8 subtiles [16col][32k], swizzled
    __shared__ _Float16 Bl[128 * 32];

    int nwg = gridDim.x;
    int cpx = nwg >> 3;
    int bid = blockIdx.x;
    int wg  = (bid & 7) * cpx + (bid >> 3);

    // bn-major (THE experiment this round): consecutive wg share one B panel
    int bm = (wg & 31) << 7;
    int bn = (wg >> 5) << 7;

    int tid  = threadIdx.x;
    int wave = tid >> 6, lane = tid & 63;
    int wr = wave >> 1, wc = wave & 1;          // 2x2 waves of 64x64
    int lrow = lane & 15, lgrp = lane >> 4;

    int colw = tid & 127;     // B staging: column within tile
    int kh   = tid >> 7;      // k-half
    int nbw  = colw >> 4;
    int colb = colw & 15;

    const float* Arow = A + (size_t)bm * KDIM;

    float4 areg[4];
    float  breg[16];
    #pragma unroll
    for (int i = 0; i < 4; ++i) {
        int idx = tid + i * 256;
        areg[i] = *(const float4*)(Arow + (size_t)(idx >> 3) * KDIM + ((idx & 7) << 2));
    }
    #pragma unroll
    for (int kk = 0; kk < 16; ++kk)
        breg[kk] = B[(size_t)(kh * 16 + kk) * FDIM + bn + colw];

    f32x4 zero = {0.0f, 0.0f, 0.0f, 0.0f};
    f32x4 acc[4][4];
    #pragma unroll
    for (int mf = 0; mf < 4; ++mf)
        #pragma unroll
        for (int nf = 0; nf < 4; ++nf) acc[mf][nf] = zero;

    for (int kt = 0; kt < KDIM; kt += 32) {
        __syncthreads();

        #pragma unroll
        for (int i = 0; i < 4; ++i) {
            int idx = tid + i * 256;
            int m   = idx >> 3;
            int g   = (idx & 7) >> 1;
            int hf  = (idx & 1) << 2;
            int off = m * 32 + ((g ^ ((m >> 1) & 3)) << 3) + hf;
            float v[4] = {areg[i].x, areg[i].y, areg[i].z, areg[i].w};
            half4v h1, h2;
            #pragma unroll
            for (int j = 0; j < 4; ++j) {
                _Float16 h = (_Float16)v[j];
                h1[j] = h;
                h2[j] = (_Float16)(v[j] - (float)h);
            }
            *(half4v*)&Ah[off] = h1;
            *(half4v*)&Al[off] = h2;
        }
        {
            half8v g0h, g0l, g1h, g1l;
            #pragma unroll
            for (int kk = 0; kk < 8; ++kk) {
                _Float16 h = (_Float16)breg[kk];
                g0h[kk] = h;
                g0l[kk] = (_Float16)(breg[kk] - (float)h);
                _Float16 h2 = (_Float16)breg[8 + kk];
                g1h[kk] = h2;
                g1l[kk] = (_Float16)(breg[8 + kk] - (float)h2);
            }
            int g0 = kh * 2, g1 = kh * 2 + 1;
            int off0 = nbw * 512 + ((colb * 4 + (g0 ^ ((colb >> 1) & 3))) << 3);
            int off1 = nbw * 512 + ((colb * 4 + (g1 ^ ((colb >> 1) & 3))) << 3);
            *(half8v*)&Bh[off0] = g0h;
            *(half8v*)&Bl[off0] = g0l;
            *(half8v*)&Bh[off1] = g1h;
            *(half8v*)&Bl[off1] = g1l;
        }
        __syncthreads();

        if (kt + 32 < KDIM) {
            #pragma unroll
            for (int i = 0; i < 4; ++i) {
                int idx = tid + i * 256;
                areg[i] = *(const float4*)(Arow + (size_t)(idx >> 3) * KDIM + kt + 32 + ((idx & 7) << 2));
            }
            #pragma unroll
            for (int kk = 0; kk < 16; ++kk)
                breg[kk] = B[(size_t)(kt + 32 + kh * 16 + kk) * FDIM + bn + colw];
        }

        half8v ahf[4], alf[4], bhf[4], blf[4];
        #pragma unroll
        for (int mf = 0; mf < 4; ++mf) {
            int m   = wr * 64 + mf * 16 + lrow;
            int off = m * 32 + ((lgrp ^ ((m >> 1) & 3)) << 3);
            ahf[mf] = *(half8v*)&Ah[off];
            alf[mf] = *(half8v*)&Al[off];
        }
        #pragma unroll
        for (int nf = 0; nf < 4; ++nf) {
            int nb  = wc * 4 + nf;
            int off = nb * 512 + ((lrow * 4 + (lgrp ^ ((lrow >> 1) & 3))) << 3);
            bhf[nf] = *(half8v*)&Bh[off];
            blf[nf] = *(half8v*)&Bl[off];
        }

        #pragma unroll
        for (int mf = 0; mf < 4; ++mf)
            #pragma unroll
            for (int nf = 0; nf < 4; ++nf) {
                acc[mf][nf] = __builtin_amdgcn_mfma_f32_16x16x32_f16(ahf[mf], bhf[nf], acc[mf][nf], 0, 0, 0);
                acc[mf][nf] = __builtin_amdgcn_mfma_f32_16x16x32_f16(ahf[mf], blf[nf], acc[mf][nf], 0, 0, 0);
                acc[mf][nf] = __builtin_amdgcn_mfma_f32_16x16x32_f16(alf[mf], bhf[nf], acc[mf][nf], 0, 0, 0);
            }
    }

    // epilogue: bias + relu (plain stores — round-4 validated)
    #pragma unroll
    for (int nf = 0; nf < 4; ++nf) {
        int col = bn + wc * 64 + nf * 16 + lrow;
        float bb = bias[col];
        #pragma unroll
        for (int mf = 0; mf < 4; ++mf) {
            int row0 = bm + wr * 64 + mf * 16 + lgrp * 4;
            #pragma unroll
            for (int r = 0; r < 4; ++r) {
                float v = acc[mf][nf][r] + bb;
                C[(size_t)(row0 + r) * FDIM + col] = (v > 0.0f) ? v : 0.0f;
            }
        }
    }
}

// ---------------------------------------------------------------------------
// Top-k with band + f64 refinement — ROUND-4 VERBATIM (known pass).
// ---------------------------------------------------------------------------
#define EPS_BAND 2e-3f
#define MAXCAND  32

__global__ __launch_bounds__(256) void topk_refine(
    float* __restrict__ feat,
    const float* __restrict__ x,      // (BATCH, KDIM)
    const float* __restrict__ Wenc,   // (KDIM, FDIM)
    const float* __restrict__ benc)   // (FDIM)
{
    int b   = blockIdx.x;
    int tid = threadIdx.x;
    float*    frow = feat + (size_t)b * FDIM;
    uint32_t* urow = (uint32_t*)frow;

    __shared__ uint32_t hist[256];
    __shared__ uint32_t scan[256];
    __shared__ uint32_t sh_prefix, sh_rem;

    // ---- phase 1: radix select bits of the 64th-largest value ----
    uint32_t prefix = 0;
    uint32_t rem    = TOPK;
    for (int byt = 3; byt >= 0; --byt) {
        hist[tid] = 0;
        __syncthreads();
        int shift_hi = (byt + 1) * 8;
        for (int i = tid; i < FDIM; i += 256) {
            uint32_t u = urow[i];
            bool match = (byt == 3) || ((u >> shift_hi) == prefix);
            if (match) atomicAdd(&hist[(u >> (byt * 8)) & 255u], 1u);
        }
        __syncthreads();
        scan[tid] = hist[255 - tid];
        __syncthreads();
        #pragma unroll
        for (int ofs = 1; ofs < 256; ofs <<= 1) {
            uint32_t tv = (tid >= ofs) ? scan[tid - ofs] : 0u;
            __syncthreads();
            scan[tid] += tv;
            __syncthreads();
        }
        uint32_t cum  = scan[tid];
        uint32_t prev = (tid == 0) ? 0u : scan[tid - 1];
        if (cum >= rem && prev < rem) {
            sh_prefix = (prefix << 8) | (uint32_t)(255 - tid);
            sh_rem    = rem - prev;
        }
        __syncthreads();
        prefix = sh_prefix;
        rem    = sh_rem;
        __syncthreads();
    }

    float T  = __uint_as_float(prefix);
    float hi = T + EPS_BAND;
    float lo = T - EPS_BAND;

    // ---- phase 2: band classify ----
    __shared__ int   s_ncand, s_ndef;
    __shared__ int   s_cidx[MAXCAND];
    __shared__ float s_cval[MAXCAND];
    __shared__ int   s_sel[MAXCAND];
    if (tid == 0) { s_ncand = 0; s_ndef = 0; }
    __syncthreads();

    int base  = tid * 64;
    int mydef = 0;
    for (int i = 0; i < 64; i += 4) {
        float4 v = *(float4*)(frow + base + i);
        float vv[4] = {v.x, v.y, v.z, v.w};
        #pragma unroll
        for (int j = 0; j < 4; ++j) {
            float val = vv[j];
            if (val > hi) {
                ++mydef;                      // definitely top-64, keep
            } else if (val >= lo) {
                int s = atomicAdd(&s_ncand, 1);
                if (s < MAXCAND) { s_cidx[s] = base + i + j; s_cval[s] = val; }
                vv[j] = 0.0f;                 // zero now, maybe restore later
            } else {
                vv[j] = 0.0f;                 // definitely out
            }
        }
        float4 w; w.x = vv[0]; w.y = vv[1]; w.z = vv[2]; w.w = vv[3];
        *(float4*)(frow + base + i) = w;
    }
    atomicAdd(&s_ndef, mydef);
    __syncthreads();

    int A    = (s_ncand < MAXCAND) ? s_ncand : MAXCAND;
    int need = TOPK - s_ndef;

    // ---- phase 3: exact f64 refinement if band has more members than slots ----
    __shared__ double red[256];
    __shared__ double s_exact[MAXCAND];
    if (A > need) {
        const float* xr = x + (size_t)b * KDIM;
        for (int c = 0; c < A; ++c) {
            int f = s_cidx[c];
            double s = 0.0;
            #pragma unroll
            for (int i = 0; i < 16; ++i) {
                int k = tid + i * 256;
                s += (double)xr[k] * (double)Wenc[(size_t)k * FDIM + f];
            }
            red[tid] = s;
            __syncthreads();
            for (int ofs = 128; ofs > 0; ofs >>= 1) {
                if (tid < ofs) red[tid] += red[tid + ofs];
                __syncthreads();
            }
            if (tid == 0) s_exact[c] = red[0] + (double)benc[f];
            __syncthreads();
        }
        if (tid == 0) {
            for (int c = 0; c < A; ++c) s_sel[c] = 0;
            for (int r = 0; r < need; ++r) {
                int best = -1;
                for (int c = 0; c < A; ++c) {
                    if (s_sel[c]) continue;
                    if (best < 0 || s_exact[c] > s_exact[best] ||
                        (s_exact[c] == s_exact[best] && s_cidx[c] < s_cidx[best]))
                        best = c;
                }
                if (best >= 0) s_sel[best] = 1;
            }
        }
    } else {
        if (tid == 0)
            for (int c = 0; c < A; ++c) s_sel[c] = 1;   // forced: restore all
    }
    __syncthreads();

    // ---- phase 4: restore selected in-band features ----
    if (tid < A && s_sel[tid]) frow[s_cidx[tid]] = s_cval[tid];
}

// ---------------------------------------------------------------------------
// Decode: one block per row; compact <=64 nonzeros; accumulate masked W_dec.
// New: hard bound on the compaction (s < TOPK) so a malformed feat row can
// never produce a wild Wdec index (fault-proofing; inert when topk correct).
// ---------------------------------------------------------------------------
__global__ __launch_bounds__(256) void decode_kernel(
    const float* __restrict__ feat,
    const float* __restrict__ Wdec,
    const float* __restrict__ bdec,
    const float* __restrict__ dmask,
    float* __restrict__ recon)
{
    int b   = blockIdx.x;
    int tid = threadIdx.x;

    __shared__ int   sidx[TOPK];
    __shared__ float sv0[TOPK], sv1[TOPK];
    __shared__ int   cnt;
    if (tid == 0) cnt = 0;
    __syncthreads();

    const float* row = feat + (size_t)b * FDIM;
    const int CHUNK = FDIM / 256;
    int base = tid * CHUNK;
    for (int i = 0; i < CHUNK; i += 4) {
        float4 v = *(const float4*)(row + base + i);
        float vv[4] = {v.x, v.y, v.z, v.w};
        #pragma unroll
        for (int j = 0; j < 4; ++j) {
            if (vv[j] != 0.0f) {
                int s = atomicAdd(&cnt, 1);
                if (s < TOPK) {
                    int f = base + i + j;
                    sidx[s] = f;
                    sv0[s]  = vv[j] * dmask[f * 2 + 0];
                    sv1[s]  = vv[j] * dmask[f * 2 + 1];
                }
            }
        }
    }
    __syncthreads();
    int n = (cnt < TOPK) ? cnt : TOPK;

    float4 acc[4];
    const float4* b4 = (const float4*)bdec;
    #pragma unroll
    for (int j = 0; j < 4; ++j) acc[j] = b4[tid + j * 256];

    for (int t = 0; t < n; ++t) {
        int f = sidx[t];
        const float4* w = (const float4*)(Wdec + (size_t)f * DDIM);
        float s0 = sv0[t], s1 = sv1[t];
        #pragma unroll
        for (int j = 0; j < 4; ++j) {
            float s = (j < 2) ? s0 : s1;
            float4 wv = w[tid + j * 256];
            acc[j].x = fmaf(s, wv.x, acc[j].x);
            acc[j].y = fmaf(s, wv.y, acc[j].y);
            acc[j].z = fmaf(s, wv.z, acc[j].z);
            acc[j].w = fmaf(s, wv.w, acc[j].w);
        }
    }

    float4* out = (float4*)(recon + (size_t)b * DDIM);
    #pragma unroll
    for (int j = 0; j < 4; ++j) out[tid + j * 256] = acc[j];
}

// ---------------------------------------------------------------------------
extern "C" void kernel_launch(void* const* d_in, const int* in_sizes, int n_in,
                              void* d_out, int out_size, void* d_ws, size_t ws_size,
                              hipStream_t stream)
{
    const float* x     = (const float*)d_in[0];
    const float* Wenc  = (const float*)d_in[1];
    const float* benc  = (const float*)d_in[2];
    const float* Wdec  = (const float*)d_in[3];
    const float* bdec  = (const float*)d_in[4];
    const float* dmask = (const float*)d_in[5];

    float* recon = (float*)d_out;
    float* feat  = recon + (size_t)BATCH * DDIM;

    encode_mfma<<<dim3((BATCH / 128) * (FDIM / 128)), 256, 0, stream>>>(x, Wenc, benc, feat);
    topk_refine<<<dim3(BATCH), 256, 0, stream>>>(feat, x, Wenc, benc);
    decode_kernel<<<dim3(BATCH), 256, 0, stream>>>(feat, Wdec, bdec, dmask, recon);
}

// Round 8
// 3341.862 us; speedup vs baseline: 2.3372x; 1.0074x over previous
//
#include <hip/hip_runtime.h>
#include <stdint.h>

#define BATCH   4096
#define KDIM    4096      // 2*2048 encode contraction
#define FDIM    16384
#define DDIM    4096
#define TOPK    64

typedef _Float16 half4v __attribute__((ext_vector_type(4)));
typedef _Float16 half8v __attribute__((ext_vector_type(8)));
typedef float    f32x4  __attribute__((ext_vector_type(4)));

// ---------------------------------------------------------------------------
// Encode: C = relu(A @ B + bias) via f16x2 split MFMA (3 products: hh, hl, lh).
// Round-7 validated verbatim (bn-major + XCD swizzle, plain stores).
// ---------------------------------------------------------------------------
__global__ __launch_bounds__(256) void encode_mfma(
    const float* __restrict__ A,
    const float* __restrict__ B,
    const float* __restrict__ bias,
    float* __restrict__ C)
{
    __shared__ _Float16 Ah[128 * 32];   // [m][k], chunk-swizzled rows of 64B
    __shared__ _Float16 Al[128 * 32];
    __shared__ _Float16 Bh[128 * 32];   // 8 subtiles [16col][32k], swizzled
    __shared__ _Float16 Bl[128 * 32];

    int nwg = gridDim.x;
    int cpx = nwg >> 3;
    int bid = blockIdx.x;
    int wg  = (bid & 7) * cpx + (bid >> 3);

    // bn-major: consecutive wg share one B panel (XCD-local B slices)
    int bm = (wg & 31) << 7;
    int bn = (wg >> 5) << 7;

    int tid  = threadIdx.x;
    int wave = tid >> 6, lane = tid & 63;
    int wr = wave >> 1, wc = wave & 1;          // 2x2 waves of 64x64
    int lrow = lane & 15, lgrp = lane >> 4;

    int colw = tid & 127;     // B staging: column within tile
    int kh   = tid >> 7;      // k-half
    int nbw  = colw >> 4;
    int colb = colw & 15;

    const float* Arow = A + (size_t)bm * KDIM;

    float4 areg[4];
    float  breg[16];
    #pragma unroll
    for (int i = 0; i < 4; ++i) {
        int idx = tid + i * 256;
        areg[i] = *(const float4*)(Arow + (size_t)(idx >> 3) * KDIM + ((idx & 7) << 2));
    }
    #pragma unroll
    for (int kk = 0; kk < 16; ++kk)
        breg[kk] = B[(size_t)(kh * 16 + kk) * FDIM + bn + colw];

    f32x4 zero = {0.0f, 0.0f, 0.0f, 0.0f};
    f32x4 acc[4][4];
    #pragma unroll
    for (int mf = 0; mf < 4; ++mf)
        #pragma unroll
        for (int nf = 0; nf < 4; ++nf) acc[mf][nf] = zero;

    for (int kt = 0; kt < KDIM; kt += 32) {
        __syncthreads();

        #pragma unroll
        for (int i = 0; i < 4; ++i) {
            int idx = tid + i * 256;
            int m   = idx >> 3;
            int g   = (idx & 7) >> 1;
            int hf  = (idx & 1) << 2;
            int off = m * 32 + ((g ^ ((m >> 1) & 3)) << 3) + hf;
            float v[4] = {areg[i].x, areg[i].y, areg[i].z, areg[i].w};
            half4v h1, h2;
            #pragma unroll
            for (int j = 0; j < 4; ++j) {
                _Float16 h = (_Float16)v[j];
                h1[j] = h;
                h2[j] = (_Float16)(v[j] - (float)h);
            }
            *(half4v*)&Ah[off] = h1;
            *(half4v*)&Al[off] = h2;
        }
        {
            half8v g0h, g0l, g1h, g1l;
            #pragma unroll
            for (int kk = 0; kk < 8; ++kk) {
                _Float16 h = (_Float16)breg[kk];
                g0h[kk] = h;
                g0l[kk] = (_Float16)(breg[kk] - (float)h);
                _Float16 h2 = (_Float16)breg[8 + kk];
                g1h[kk] = h2;
                g1l[kk] = (_Float16)(breg[8 + kk] - (float)h2);
            }
            int g0 = kh * 2, g1 = kh * 2 + 1;
            int off0 = nbw * 512 + ((colb * 4 + (g0 ^ ((colb >> 1) & 3))) << 3);
            int off1 = nbw * 512 + ((colb * 4 + (g1 ^ ((colb >> 1) & 3))) << 3);
            *(half8v*)&Bh[off0] = g0h;
            *(half8v*)&Bl[off0] = g0l;
            *(half8v*)&Bh[off1] = g1h;
            *(half8v*)&Bl[off1] = g1l;
        }
        __syncthreads();

        if (kt + 32 < KDIM) {
            #pragma unroll
            for (int i = 0; i < 4; ++i) {
                int idx = tid + i * 256;
                areg[i] = *(const float4*)(Arow + (size_t)(idx >> 3) * KDIM + kt + 32 + ((idx & 7) << 2));
            }
            #pragma unroll
            for (int kk = 0; kk < 16; ++kk)
                breg[kk] = B[(size_t)(kt + 32 + kh * 16 + kk) * FDIM + bn + colw];
        }

        half8v ahf[4], alf[4], bhf[4], blf[4];
        #pragma unroll
        for (int mf = 0; mf < 4; ++mf) {
            int m   = wr * 64 + mf * 16 + lrow;
            int off = m * 32 + ((lgrp ^ ((m >> 1) & 3)) << 3);
            ahf[mf] = *(half8v*)&Ah[off];
            alf[mf] = *(half8v*)&Al[off];
        }
        #pragma unroll
        for (int nf = 0; nf < 4; ++nf) {
            int nb  = wc * 4 + nf;
            int off = nb * 512 + ((lrow * 4 + (lgrp ^ ((lrow >> 1) & 3))) << 3);
            bhf[nf] = *(half8v*)&Bh[off];
            blf[nf] = *(half8v*)&Bl[off];
        }

        #pragma unroll
        for (int mf = 0; mf < 4; ++mf)
            #pragma unroll
            for (int nf = 0; nf < 4; ++nf) {
                acc[mf][nf] = __builtin_amdgcn_mfma_f32_16x16x32_f16(ahf[mf], bhf[nf], acc[mf][nf], 0, 0, 0);
                acc[mf][nf] = __builtin_amdgcn_mfma_f32_16x16x32_f16(ahf[mf], blf[nf], acc[mf][nf], 0, 0, 0);
                acc[mf][nf] = __builtin_amdgcn_mfma_f32_16x16x32_f16(alf[mf], bhf[nf], acc[mf][nf], 0, 0, 0);
            }
    }

    // epilogue: bias + relu (plain stores)
    #pragma unroll
    for (int nf = 0; nf < 4; ++nf) {
        int col = bn + wc * 64 + nf * 16 + lrow;
        float bb = bias[col];
        #pragma unroll
        for (int mf = 0; mf < 4; ++mf) {
            int row0 = bm + wr * 64 + mf * 16 + lgrp * 4;
            #pragma unroll
            for (int r = 0; r < 4; ++r) {
                float v = acc[mf][nf][r] + bb;
                C[(size_t)(row0 + r) * FDIM + col] = (v > 0.0f) ? v : 0.0f;
            }
        }
    }
}

// ---------------------------------------------------------------------------
// Top-k with band + f64 refinement. Round-7 structure; TWO edits:
//  - EPS_BAND 2e-3 -> 2e-5 (fast-path error is ~2e-6; 2e-3 was 100x too wide
//    and sent ~42% of rows into the expensive strided f64 gather)
//  - zero-skip in radix pass 3 (nz ~= 8192 >> 64, zeros can't reach rank 64;
//    kills ~8k serialized same-address LDS atomics per row)
// ---------------------------------------------------------------------------
#define EPS_BAND 2e-5f
#define MAXCAND  32

__global__ __launch_bounds__(256) void topk_refine(
    float* __restrict__ feat,
    const float* __restrict__ x,      // (BATCH, KDIM)
    const float* __restrict__ Wenc,   // (KDIM, FDIM)
    const float* __restrict__ benc)   // (FDIM)
{
    int b   = blockIdx.x;
    int tid = threadIdx.x;
    float*    frow = feat + (size_t)b * FDIM;
    uint32_t* urow = (uint32_t*)frow;

    __shared__ uint32_t hist[256];
    __shared__ uint32_t scan[256];
    __shared__ uint32_t sh_prefix, sh_rem;

    // ---- phase 1: radix select bits of the 64th-largest value ----
    uint32_t prefix = 0;
    uint32_t rem    = TOPK;
    for (int byt = 3; byt >= 0; --byt) {
        hist[tid] = 0;
        __syncthreads();
        int shift_hi = (byt + 1) * 8;
        for (int i = tid; i < FDIM; i += 256) {
            uint32_t u = urow[i];
            if (byt == 3) {
                if (u) atomicAdd(&hist[u >> 24], 1u);   // skip relu zeros
            } else {
                if ((u >> shift_hi) == prefix)
                    atomicAdd(&hist[(u >> (byt * 8)) & 255u], 1u);
            }
        }
        __syncthreads();
        scan[tid] = hist[255 - tid];
        __syncthreads();
        #pragma unroll
        for (int ofs = 1; ofs < 256; ofs <<= 1) {
            uint32_t tv = (tid >= ofs) ? scan[tid - ofs] : 0u;
            __syncthreads();
            scan[tid] += tv;
            __syncthreads();
        }
        uint32_t cum  = scan[tid];
        uint32_t prev = (tid == 0) ? 0u : scan[tid - 1];
        if (cum >= rem && prev < rem) {
            sh_prefix = (prefix << 8) | (uint32_t)(255 - tid);
            sh_rem    = rem - prev;
        }
        __syncthreads();
        prefix = sh_prefix;
        rem    = sh_rem;
        __syncthreads();
    }

    float T  = __uint_as_float(prefix);
    float hi = T + EPS_BAND;
    float lo = T - EPS_BAND;

    // ---- phase 2: band classify ----
    __shared__ int   s_ncand, s_ndef;
    __shared__ int   s_cidx[MAXCAND];
    __shared__ float s_cval[MAXCAND];
    __shared__ int   s_sel[MAXCAND];
    if (tid == 0) { s_ncand = 0; s_ndef = 0; }
    __syncthreads();

    int base  = tid * 64;
    int mydef = 0;
    for (int i = 0; i < 64; i += 4) {
        float4 v = *(float4*)(frow + base + i);
        float vv[4] = {v.x, v.y, v.z, v.w};
        #pragma unroll
        for (int j = 0; j < 4; ++j) {
            float val = vv[j];
            if (val > hi) {
                ++mydef;                      // definitely top-64, keep
            } else if (val >= lo) {
                int s = atomicAdd(&s_ncand, 1);
                if (s < MAXCAND) { s_cidx[s] = base + i + j; s_cval[s] = val; }
                vv[j] = 0.0f;                 // zero now, maybe restore later
            } else {
                vv[j] = 0.0f;                 // definitely out
            }
        }
        float4 w; w.x = vv[0]; w.y = vv[1]; w.z = vv[2]; w.w = vv[3];
        *(float4*)(frow + base + i) = w;
    }
    atomicAdd(&s_ndef, mydef);
    __syncthreads();

    int A    = (s_ncand < MAXCAND) ? s_ncand : MAXCAND;
    int need = TOPK - s_ndef;

    // ---- phase 3: exact f64 refinement if band has more members than slots ----
    __shared__ double red[256];
    __shared__ double s_exact[MAXCAND];
    if (A > need) {
        const float* xr = x + (size_t)b * KDIM;
        for (int c = 0; c < A; ++c) {
            int f = s_cidx[c];
            double s = 0.0;
            #pragma unroll
            for (int i = 0; i < 16; ++i) {
                int k = tid + i * 256;
                s += (double)xr[k] * (double)Wenc[(size_t)k * FDIM + f];
            }
            red[tid] = s;
            __syncthreads();
            for (int ofs = 128; ofs > 0; ofs >>= 1) {
                if (tid < ofs) red[tid] += red[tid + ofs];
                __syncthreads();
            }
            if (tid == 0) s_exact[c] = red[0] + (double)benc[f];
            __syncthreads();
        }
        if (tid == 0) {
            for (int c = 0; c < A; ++c) s_sel[c] = 0;
            for (int r = 0; r < need; ++r) {
                int best = -1;
                for (int c = 0; c < A; ++c) {
                    if (s_sel[c]) continue;
                    if (best < 0 || s_exact[c] > s_exact[best] ||
                        (s_exact[c] == s_exact[best] && s_cidx[c] < s_cidx[best]))
                        best = c;
                }
                if (best >= 0) s_sel[best] = 1;
            }
        }
    } else {
        if (tid == 0)
            for (int c = 0; c < A; ++c) s_sel[c] = 1;   // forced: restore all
    }
    __syncthreads();

    // ---- phase 4: restore selected in-band features ----
    if (tid < A && s_sel[tid]) frow[s_cidx[tid]] = s_cval[tid];
}

// ---------------------------------------------------------------------------
// Decode: one block per row; compact <=64 nonzeros; accumulate masked W_dec.
// ---------------------------------------------------------------------------
__global__ __launch_bounds__(256) void decode_kernel(
    const float* __restrict__ feat,
    const float* __restrict__ Wdec,
    const float* __restrict__ bdec,
    const float* __restrict__ dmask,
    float* __restrict__ recon)
{
    int b   = blockIdx.x;
    int tid = threadIdx.x;

    __shared__ int   sidx[TOPK];
    __shared__ float sv0[TOPK], sv1[TOPK];
    __shared__ int   cnt;
    if (tid == 0) cnt = 0;
    __syncthreads();

    const float* row = feat + (size_t)b * FDIM;
    const int CHUNK = FDIM / 256;
    int base = tid * CHUNK;
    for (int i = 0; i < CHUNK; i += 4) {
        float4 v = *(const float4*)(row + base + i);
        float vv[4] = {v.x, v.y, v.z, v.w};
        #pragma unroll
        for (int j = 0; j < 4; ++j) {
            if (vv[j] != 0.0f) {
                int s = atomicAdd(&cnt, 1);
                if (s < TOPK) {
                    int f = base + i + j;
                    sidx[s] = f;
                    sv0[s]  = vv[j] * dmask[f * 2 + 0];
                    sv1[s]  = vv[j] * dmask[f * 2 + 1];
                }
            }
        }
    }
    __syncthreads();
    int n = (cnt < TOPK) ? cnt : TOPK;

    float4 acc[4];
    const float4* b4 = (const float4*)bdec;
    #pragma unroll
    for (int j = 0; j < 4; ++j) acc[j] = b4[tid + j * 256];

    for (int t = 0; t < n; ++t) {
        int f = sidx[t];
        const float4* w = (const float4*)(Wdec + (size_t)f * DDIM);
        float s0 = sv0[t], s1 = sv1[t];
        #pragma unroll
        for (int j = 0; j < 4; ++j) {
            float s = (j < 2) ? s0 : s1;
            float4 wv = w[tid + j * 256];
            acc[j].x = fmaf(s, wv.x, acc[j].x);
            acc[j].y = fmaf(s, wv.y, acc[j].y);
            acc[j].z = fmaf(s, wv.z, acc[j].z);
            acc[j].w = fmaf(s, wv.w, acc[j].w);
        }
    }

    float4* out = (float4*)(recon + (size_t)b * DDIM);
    #pragma unroll
    for (int j = 0; j < 4; ++j) out[tid + j * 256] = acc[j];
}

// ---------------------------------------------------------------------------
extern "C" void kernel_launch(void* const* d_in, const int* in_sizes, int n_in,
                              void* d_out, int out_size, void* d_ws, size_t ws_size,
                              hipStream_t stream)
{
    const float* x     = (const float*)d_in[0];
    const float* Wenc  = (const float*)d_in[1];
    const float* benc  = (const float*)d_in[2];
    const float* Wdec  = (const float*)d_in[3];
    const float* bdec  = (const float*)d_in[4];
    const float* dmask = (const float*)d_in[5];

    float* recon = (float*)d_out;
    float* feat  = recon + (size_t)BATCH * DDIM;

    encode_mfma<<<dim3((BATCH / 128) * (FDIM / 128)), 256, 0, stream>>>(x, Wenc, benc, feat);
    topk_refine<<<dim3(BATCH), 256, 0, stream>>>(feat, x, Wenc, benc);
    decode_kernel<<<dim3(BATCH), 256, 0, stream>>>(feat, Wdec, bdec, dmask, recon);
}

// Round 9
// 2778.651 us; speedup vs baseline: 2.8109x; 1.2027x over previous
//
#include <hip/hip_runtime.h>
#include <stdint.h>

#define BATCH   4096
#define KDIM    4096      // 2*2048 encode contraction
#define FDIM    16384
#define DDIM    4096
#define TOPK    64

typedef _Float16 half4v __attribute__((ext_vector_type(4)));
typedef _Float16 half8v __attribute__((ext_vector_type(8)));
typedef float    f32x4  __attribute__((ext_vector_type(4)));

// ---------------------------------------------------------------------------
// Encode: C = relu(A @ B + bias) via f16x2 split MFMA (3 products: hh, hl, lh).
// Round-7/8 validated verbatim (bn-major + XCD swizzle, plain stores).
// ---------------------------------------------------------------------------
__global__ __launch_bounds__(256) void encode_mfma(
    const float* __restrict__ A,
    const float* __restrict__ B,
    const float* __restrict__ bias,
    float* __restrict__ C)
{
    __shared__ _Float16 Ah[128 * 32];   // [m][k], chunk-swizzled rows of 64B
    __shared__ _Float16 Al[128 * 32];
    __shared__ _Float16 Bh[128 * 32];   // 8 subtiles [16col][32k], swizzled
    __shared__ _Float16 Bl[128 * 32];

    int nwg = gridDim.x;
    int cpx = nwg >> 3;
    int bid = blockIdx.x;
    int wg  = (bid & 7) * cpx + (bid >> 3);

    // bn-major: consecutive wg share one B panel (XCD-local B slices)
    int bm = (wg & 31) << 7;
    int bn = (wg >> 5) << 7;

    int tid  = threadIdx.x;
    int wave = tid >> 6, lane = tid & 63;
    int wr = wave >> 1, wc = wave & 1;          // 2x2 waves of 64x64
    int lrow = lane & 15, lgrp = lane >> 4;

    int colw = tid & 127;     // B staging: column within tile
    int kh   = tid >> 7;      // k-half
    int nbw  = colw >> 4;
    int colb = colw & 15;

    const float* Arow = A + (size_t)bm * KDIM;

    float4 areg[4];
    float  breg[16];
    #pragma unroll
    for (int i = 0; i < 4; ++i) {
        int idx = tid + i * 256;
        areg[i] = *(const float4*)(Arow + (size_t)(idx >> 3) * KDIM + ((idx & 7) << 2));
    }
    #pragma unroll
    for (int kk = 0; kk < 16; ++kk)
        breg[kk] = B[(size_t)(kh * 16 + kk) * FDIM + bn + colw];

    f32x4 zero = {0.0f, 0.0f, 0.0f, 0.0f};
    f32x4 acc[4][4];
    #pragma unroll
    for (int mf = 0; mf < 4; ++mf)
        #pragma unroll
        for (int nf = 0; nf < 4; ++nf) acc[mf][nf] = zero;

    for (int kt = 0; kt < KDIM; kt += 32) {
        __syncthreads();

        #pragma unroll
        for (int i = 0; i < 4; ++i) {
            int idx = tid + i * 256;
            int m   = idx >> 3;
            int g   = (idx & 7) >> 1;
            int hf  = (idx & 1) << 2;
            int off = m * 32 + ((g ^ ((m >> 1) & 3)) << 3) + hf;
            float v[4] = {areg[i].x, areg[i].y, areg[i].z, areg[i].w};
            half4v h1, h2;
            #pragma unroll
            for (int j = 0; j < 4; ++j) {
                _Float16 h = (_Float16)v[j];
                h1[j] = h;
                h2[j] = (_Float16)(v[j] - (float)h);
            }
            *(half4v*)&Ah[off] = h1;
            *(half4v*)&Al[off] = h2;
        }
        {
            half8v g0h, g0l, g1h, g1l;
            #pragma unroll
            for (int kk = 0; kk < 8; ++kk) {
                _Float16 h = (_Float16)breg[kk];
                g0h[kk] = h;
                g0l[kk] = (_Float16)(breg[kk] - (float)h);
                _Float16 h2 = (_Float16)breg[8 + kk];
                g1h[kk] = h2;
                g1l[kk] = (_Float16)(breg[8 + kk] - (float)h2);
            }
            int g0 = kh * 2, g1 = kh * 2 + 1;
            int off0 = nbw * 512 + ((colb * 4 + (g0 ^ ((colb >> 1) & 3))) << 3);
            int off1 = nbw * 512 + ((colb * 4 + (g1 ^ ((colb >> 1) & 3))) << 3);
            *(half8v*)&Bh[off0] = g0h;
            *(half8v*)&Bl[off0] = g0l;
            *(half8v*)&Bh[off1] = g1h;
            *(half8v*)&Bl[off1] = g1l;
        }
        __syncthreads();

        if (kt + 32 < KDIM) {
            #pragma unroll
            for (int i = 0; i < 4; ++i) {
                int idx = tid + i * 256;
                areg[i] = *(const float4*)(Arow + (size_t)(idx >> 3) * KDIM + kt + 32 + ((idx & 7) << 2));
            }
            #pragma unroll
            for (int kk = 0; kk < 16; ++kk)
                breg[kk] = B[(size_t)(kt + 32 + kh * 16 + kk) * FDIM + bn + colw];
        }

        half8v ahf[4], alf[4], bhf[4], blf[4];
        #pragma unroll
        for (int mf = 0; mf < 4; ++mf) {
            int m   = wr * 64 + mf * 16 + lrow;
            int off = m * 32 + ((lgrp ^ ((m >> 1) & 3)) << 3);
            ahf[mf] = *(half8v*)&Ah[off];
            alf[mf] = *(half8v*)&Al[off];
        }
        #pragma unroll
        for (int nf = 0; nf < 4; ++nf) {
            int nb  = wc * 4 + nf;
            int off = nb * 512 + ((lrow * 4 + (lgrp ^ ((lrow >> 1) & 3))) << 3);
            bhf[nf] = *(half8v*)&Bh[off];
            blf[nf] = *(half8v*)&Bl[off];
        }

        #pragma unroll
        for (int mf = 0; mf < 4; ++mf)
            #pragma unroll
            for (int nf = 0; nf < 4; ++nf) {
                acc[mf][nf] = __builtin_amdgcn_mfma_f32_16x16x32_f16(ahf[mf], bhf[nf], acc[mf][nf], 0, 0, 0);
                acc[mf][nf] = __builtin_amdgcn_mfma_f32_16x16x32_f16(ahf[mf], blf[nf], acc[mf][nf], 0, 0, 0);
                acc[mf][nf] = __builtin_amdgcn_mfma_f32_16x16x32_f16(alf[mf], bhf[nf], acc[mf][nf], 0, 0, 0);
            }
    }

    // epilogue: bias + relu (plain stores)
    #pragma unroll
    for (int nf = 0; nf < 4; ++nf) {
        int col = bn + wc * 64 + nf * 16 + lrow;
        float bb = bias[col];
        #pragma unroll
        for (int mf = 0; mf < 4; ++mf) {
            int row0 = bm + wr * 64 + mf * 16 + lgrp * 4;
            #pragma unroll
            for (int r = 0; r < 4; ++r) {
                float v = acc[mf][nf][r] + bb;
                C[(size_t)(row0 + r) * FDIM + col] = (v > 0.0f) ? v : 0.0f;
            }
        }
    }
}

// ---------------------------------------------------------------------------
// Fused top-k + decode. 512 threads; row lives in 32 VGPRs/thread (static
// indexing only). One global read of the row; radix passes 2-4 scan registers.
// Band + f64 refinement logic is the round-4/7/8-validated algorithm.
// Survivors are compacted in LDS with dec_mask pre-applied -> Wdec gather
// runs immediately (no feat re-read, no third kernel).
// ---------------------------------------------------------------------------
#define EPS_BAND 2e-5f
#define MAXCAND  32
#define LISTCAP  96

__global__ __launch_bounds__(512) void topk_decode(
    float* __restrict__ feat,
    const float* __restrict__ x,      // (BATCH, KDIM)
    const float* __restrict__ Wenc,   // (KDIM, FDIM)
    const float* __restrict__ benc,   // (FDIM)
    const float* __restrict__ Wdec,   // (FDIM, DDIM)
    const float* __restrict__ bdec,   // (DDIM)
    const float* __restrict__ dmask,  // (FDIM, 2)
    float* __restrict__ recon)        // (BATCH, DDIM)
{
    int b   = blockIdx.x;
    int tid = threadIdx.x;
    int wv  = tid >> 6;               // wave 0..7
    float* frow = feat + (size_t)b * FDIM;

    // ---- load row into registers (stride-512: coalesced) ----
    float r[32];
    #pragma unroll
    for (int i = 0; i < 32; ++i) r[i] = frow[tid + i * 512];

    __shared__ uint32_t hist[8][256];
    __shared__ uint32_t scan[256];
    __shared__ uint32_t sh_prefix, sh_rem;
    __shared__ int   s_ncand, s_ndef, s_n;
    __shared__ int   s_cidx[MAXCAND];
    __shared__ float s_cval[MAXCAND];
    __shared__ int   s_sel[MAXCAND];
    __shared__ int   L_idx[LISTCAP];
    __shared__ float L_v0[LISTCAP], L_v1[LISTCAP];
    __shared__ double red[512];
    __shared__ double s_exact[MAXCAND];

    if (tid == 0) { s_ncand = 0; s_ndef = 0; s_n = 0; }

    // ---- radix pass on top byte (exponent) ----
    #pragma unroll
    for (int i = 0; i < 4; ++i) ((uint32_t*)hist)[tid + i * 512] = 0u;
    __syncthreads();
    #pragma unroll
    for (int i = 0; i < 32; ++i) {
        uint32_t u = __float_as_uint(r[i]);
        if (u) atomicAdd(&hist[wv][u >> 24], 1u);   // skip relu zeros
    }
    __syncthreads();
    if (tid < 256) {
        int rb = 255 - tid;
        uint32_t s = 0;
        #pragma unroll
        for (int w = 0; w < 8; ++w) s += hist[w][rb];
        scan[tid] = s;
    }
    __syncthreads();
    #pragma unroll
    for (int ofs = 1; ofs < 256; ofs <<= 1) {
        uint32_t tv = 0;
        if (tid < 256 && tid >= ofs) tv = scan[tid - ofs];
        __syncthreads();
        if (tid < 256) scan[tid] += tv;
        __syncthreads();
    }
    bool small = (scan[255] <= TOPK);   // uniform across block

    uint32_t prefix = 0, rem = TOPK;
    if (!small) {
        if (tid < 256) {
            uint32_t cum  = scan[tid];
            uint32_t prev = (tid == 0) ? 0u : scan[tid - 1];
            if (cum >= rem && prev < rem) {
                sh_prefix = (uint32_t)(255 - tid);
                sh_rem    = rem - prev;
            }
        }
        __syncthreads();
        prefix = sh_prefix;
        rem    = sh_rem;
        __syncthreads();

        // ---- radix passes on bytes 2,1,0: scan REGISTERS only ----
        for (int byt = 2; byt >= 0; --byt) {
            #pragma unroll
            for (int i = 0; i < 4; ++i) ((uint32_t*)hist)[tid + i * 512] = 0u;
            __syncthreads();
            int shift_hi = (byt + 1) * 8;
            #pragma unroll
            for (int i = 0; i < 32; ++i) {
                uint32_t u = __float_as_uint(r[i]);
                if ((u >> shift_hi) == prefix)
                    atomicAdd(&hist[wv][(u >> (byt * 8)) & 255u], 1u);
            }
            __syncthreads();
            if (tid < 256) {
                int rb = 255 - tid;
                uint32_t s = 0;
                #pragma unroll
                for (int w = 0; w < 8; ++w) s += hist[w][rb];
                scan[tid] = s;
            }
            __syncthreads();
            #pragma unroll
            for (int ofs = 1; ofs < 256; ofs <<= 1) {
                uint32_t tv = 0;
                if (tid < 256 && tid >= ofs) tv = scan[tid - ofs];
                __syncthreads();
                if (tid < 256) scan[tid] += tv;
                __syncthreads();
            }
            if (tid < 256) {
                uint32_t cum  = scan[tid];
                uint32_t prev = (tid == 0) ? 0u : scan[tid - 1];
                if (cum >= rem && prev < rem) {
                    sh_prefix = (prefix << 8) | (uint32_t)(255 - tid);
                    sh_rem    = rem - prev;
                }
            }
            __syncthreads();
            prefix = sh_prefix;
            rem    = sh_rem;
            __syncthreads();
        }

        float T  = __uint_as_float(prefix);
        float hi = T + EPS_BAND;
        float lo = T - EPS_BAND;

        // ---- classify from registers; build decode list; write feat ----
        int mydef = 0;
        #pragma unroll
        for (int i = 0; i < 32; ++i) {
            float val = r[i];
            int   f   = tid + i * 512;
            if (val > hi) {
                ++mydef;
                int s = atomicAdd(&s_n, 1);
                if (s < LISTCAP) {
                    L_idx[s] = f;
                    L_v0[s]  = val * dmask[2 * f + 0];
                    L_v1[s]  = val * dmask[2 * f + 1];
                }
            } else if (val >= lo && val > 0.0f) {
                int s = atomicAdd(&s_ncand, 1);
                if (s < MAXCAND) { s_cidx[s] = f; s_cval[s] = val; }
                r[i] = 0.0f;
            } else {
                r[i] = 0.0f;
            }
        }
        atomicAdd(&s_ndef, mydef);
        #pragma unroll
        for (int i = 0; i < 32; ++i) frow[tid + i * 512] = r[i];
        __syncthreads();

        int A    = (s_ncand < MAXCAND) ? s_ncand : MAXCAND;
        int need = TOPK - s_ndef;

        // ---- f64 refinement when band has more members than slots ----
        if (A > need) {
            const float* xr = x + (size_t)b * KDIM;
            for (int c = 0; c < A; ++c) {
                int f = s_cidx[c];
                double s = 0.0;
                #pragma unroll
                for (int i = 0; i < 8; ++i) {
                    int k = tid + i * 512;
                    s += (double)xr[k] * (double)Wenc[(size_t)k * FDIM + f];
                }
                red[tid] = s;
                __syncthreads();
                for (int ofs = 256; ofs > 0; ofs >>= 1) {
                    if (tid < ofs) red[tid] += red[tid + ofs];
                    __syncthreads();
                }
                if (tid == 0) s_exact[c] = red[0] + (double)benc[f];
                __syncthreads();
            }
            if (tid == 0) {
                for (int c = 0; c < A; ++c) s_sel[c] = 0;
                for (int rr = 0; rr < need; ++rr) {
                    int best = -1;
                    for (int c = 0; c < A; ++c) {
                        if (s_sel[c]) continue;
                        if (best < 0 || s_exact[c] > s_exact[best] ||
                            (s_exact[c] == s_exact[best] && s_cidx[c] < s_cidx[best]))
                            best = c;
                    }
                    if (best >= 0) s_sel[best] = 1;
                }
            }
        } else {
            if (tid == 0)
                for (int c = 0; c < A; ++c) s_sel[c] = 1;   // forced: keep all
        }
        __syncthreads();

        // ---- restore selected in-band features; append to decode list ----
        if (tid < A && s_sel[tid]) {
            int   f   = s_cidx[tid];
            float val = s_cval[tid];
            frow[f] = val;
            int s = atomicAdd(&s_n, 1);
            if (s < LISTCAP) {
                L_idx[s] = f;
                L_v0[s]  = val * dmask[2 * f + 0];
                L_v1[s]  = val * dmask[2 * f + 1];
            }
        }
        __syncthreads();
    } else {
        // ---- nz <= 64: row already equals its top-k; just compact ----
        #pragma unroll
        for (int i = 0; i < 32; ++i) {
            float val = r[i];
            if (val != 0.0f) {
                int f = tid + i * 512;
                int s = atomicAdd(&s_n, 1);
                if (s < LISTCAP) {
                    L_idx[s] = f;
                    L_v0[s]  = val * dmask[2 * f + 0];
                    L_v1[s]  = val * dmask[2 * f + 1];
                }
            }
        }
        __syncthreads();
    }

    int n = (s_n < LISTCAP) ? s_n : LISTCAP;

    // ---- decode: recon[b] = sum_f val_f * Wdec_masked[f] + bdec ----
    // thread covers float4 elems [4*tid,4*tid+4) (model 0 half) and
    // [4*(tid+512), ...) (model 1 half) -> clean s0/s1 split.
    const float4* b4 = (const float4*)bdec;
    float4 a0 = b4[tid];
    float4 a1 = b4[tid + 512];

    for (int t = 0; t < n; ++t) {
        int f = L_idx[t];
        float s0 = L_v0[t], s1 = L_v1[t];
        const float4* w = (const float4*)(Wdec + (size_t)f * DDIM);
        float4 w0 = w[tid];
        float4 w1 = w[tid + 512];
        a0.x = fmaf(s0, w0.x, a0.x); a0.y = fmaf(s0, w0.y, a0.y);
        a0.z = fmaf(s0, w0.z, a0.z); a0.w = fmaf(s0, w0.w, a0.w);
        a1.x = fmaf(s1, w1.x, a1.x); a1.y = fmaf(s1, w1.y, a1.y);
        a1.z = fmaf(s1, w1.z, a1.z); a1.w = fmaf(s1, w1.w, a1.w);
    }

    float4* out = (float4*)(recon + (size_t)b * DDIM);
    out[tid]       = a0;
    out[tid + 512] = a1;
}

// ---------------------------------------------------------------------------
extern "C" void kernel_launch(void* const* d_in, const int* in_sizes, int n_in,
                              void* d_out, int out_size, void* d_ws, size_t ws_size,
                              hipStream_t stream)
{
    const float* x     = (const float*)d_in[0];
    const float* Wenc  = (const float*)d_in[1];
    const float* benc  = (const float*)d_in[2];
    const float* Wdec  = (const float*)d_in[3];
    const float* bdec  = (const float*)d_in[4];
    const float* dmask = (const float*)d_in[5];

    float* recon = (float*)d_out;
    float* feat  = recon + (size_t)BATCH * DDIM;

    encode_mfma<<<dim3((BATCH / 128) * (FDIM / 128)), 256, 0, stream>>>(x, Wenc, benc, feat);
    topk_decode<<<dim3(BATCH), 512, 0, stream>>>(feat, x, Wenc, benc, Wdec, bdec, dmask, recon);
}